// Round 12
// baseline (765.507 us; speedup 1.0000x reference)
//
#include <hip/hip_runtime.h>
#include <cstdint>
#include <cstddef>

#define T_LEN 16384
#define BATCH 8
#define NLAYER 9

typedef _Float16 f16;
typedef __attribute__((ext_vector_type(8))) _Float16 f16x8;
typedef __attribute__((ext_vector_type(4))) float f32x4;
#define MFMA_F16 __builtin_amdgcn_mfma_f32_16x16x32_f16
#define PIN() __builtin_amdgcn_sched_barrier(0)

// async global->LDS DMA, 16 B per lane (dst = wave-uniform base + lane*16)
__device__ __forceinline__ void stage16(const f16* g, f16* l) {
    __builtin_amdgcn_global_load_lds(
        (const __attribute__((address_space(1))) unsigned int*)g,
        (__attribute__((address_space(3))) unsigned int*)l, 16, 0, 0);
}

__device__ __forceinline__ float fast_tanh(float x) {
    return 1.0f - 2.0f / (__expf(2.0f * x) + 1.0f);
}

// ---------------------------------------------------------------------------
// Weight prepack to fp16, B-fragment order [n][k32-chunk].  (round-4 layout)
//  wA [12][256][32] pre-swizzled per row (slot i holds logical k-group
//  i ^ ((n>>1)&3)); rows 0-127 = filters, 128-255 = gates.
//  wB [4][256][32] linear; 128 f16 of ZEROS appended (zpad: the layer
//  kernel's out-of-range A-loads read this instead of doing value-selects).
// ---------------------------------------------------------------------------
__global__ __launch_bounds__(256) void prep_weights(
    const float* __restrict__ cw, const float* __restrict__ ow,
    const float* __restrict__ o1w, f16* __restrict__ wA, f16* __restrict__ wB)
{
    int n = blockIdx.x * 256 + threadIdx.x;
    const int NA = NLAYER * 12 * 256 * 32;   // 884736
    const int NB = NLAYER * 4 * 256 * 32;    // 294912
    if (n < NA) {
        int kp = n & 31; int q = n >> 5;
        int c = q & 255; q >>= 8;
        int ch = q % 12; int l = q / 12;
        int i = kp >> 3, j = kp & 7;
        int il = i ^ ((c >> 1) & 3);
        int kpl = il * 8 + j;
        int tap = ch >> 2;
        int r = (ch & 3) * 32 + kpl;
        wA[n] = (f16)cw[((size_t)(l * 256 + c) * 128 + r) * 3 + tap];
    } else if (n < NA + NB) {
        int m = n - NA;
        int kp = m & 31; int q = m >> 5;
        int c = q & 255; q >>= 8;
        int ch = q & 3; int l = q >> 2;
        int k = ch * 32 + kp;
        float v = (c < 128) ? ow[(size_t)(l * 128 + c) * 128 + k]
                            : o1w[(size_t)(c - 128) * 1152 + l * 128 + k];
        wB[m] = (f16)v;
    } else if (n < NA + NB + 128) {
        wB[n - NA] = (f16)0.0f;    // zpad row (128 f16 of zeros)
    }
}

// h[b][t][r] = tanh(iw[r]*x[b][t] + ib[r]) (fp16);  acc1 zero-init (fp16)
__global__ __launch_bounds__(256) void input_init(
    const float* __restrict__ x, const float* __restrict__ iw,
    const float* __restrict__ ib,
    f16* __restrict__ h, f16* __restrict__ acc1)
{
    int n = blockIdx.x * 256 + threadIdx.x;
    int r = n & 127; int bt = n >> 7;
    h[n] = (f16)fast_tanh(iw[r] * x[bt] + ib[r]);
    acc1[n] = (f16)0.0f;
}

// ---------------------------------------------------------------------------
// One layer, fused. 256 thr = 4 waves. Block M=64 x N=256; wave M=32 x N=128.
//
// ROUND-12: cross-era ds_read->MFMA pipeline, with COMPILER-PROOF issue
// order. r11's corruption: the vmcnt ledger assumed VMEM issue order =
// program order, but LLVM may legally reorder global_load_lds vs global
// loads (no alias: LDS-write vs global-read). Fix: sched_barrier(0) PIN
// between every VMEM-issuing group, so issue order is exactly:
//   era hc: [DMA(hc+2)] PIN [readB(hc)->fr[hc&1] (ds)] PIN
//           [MFMA(chunk hc-1) from fr[(hc-1)&1]] PIN
//           [loadA(tap) only at hc==8/16, AFTER MFMA (r6 rule)] PIN
//           [vmcnt ledger] barrier PIN
// A-loads use a ZERO-PAGE ADDRESS select (zpad) instead of value-selects,
// so no compiler-inserted mid-era drains (selects would need the loaded
// value; address select needs nothing).
// vmcnt ledger (loads; exact under pins, event-simulated):
//   prologue vmcnt(10) [D0 retired, D1+A(8) in flight]; e0 vmcnt(10);
//   e1-7 vmcnt(2); e8 vmcnt(10) [keeps loadA(1) x8 in flight]; e9-15
//   vmcnt(2); e16 vmcnt(10); e17-21 vmcnt(2); e22 vmcnt(0); e23 none.
//   (At e1/e9/e17 the compiler inserts its own vmcnt before the first
//   tap-consuming MFMA to retire the A-loads; over-drains one DMA pair —
//   harmless.)
// fr[2][4] cross-era double buffer: each ds_read gets a full era of cover;
// the compiler's lgkmcnt(4) before the MFMA cluster waits only on LAST
// era's reads. This is the r10/r11 theory (LDS-read serialization under the
// zero-spare-reg (256,4) budget) finally tested on a correct kernel; fr+a
// need (256,3) [170 regs].
// Phase 2 / gating / epilogue: r9 VERBATIM (passed twice) — removes the
// az-batching suspect that r10/r11 shared.
// DO NOT go below (256,3): r1's 64-reg cap spilled acc (6x regression).
// ---------------------------------------------------------------------------
__global__ __launch_bounds__(256, 3) void layer_kernel(
    const f16* __restrict__ h_in, f16* __restrict__ h_out,
    f16* __restrict__ acc1,
    const f16* __restrict__ wA,   // [12][256][32] this layer (pre-swizzled)
    const f16* __restrict__ wB,   // [4][256][32]  this layer (linear)
    const f16* __restrict__ zpad, // 128 f16 zeros
    const float* __restrict__ cb, // conv_b [256]
    const float* __restrict__ ob, // out_b  [128]
    int d)
{
    __shared__ __align__(16) char smem_raw[34816];
    f16* const Bsm = (f16*)smem_raw;            // phase 1: 4 bufs x 4096 f16
    f16* const zsR = (f16*)smem_raw;            // z, then res: [64][136]
    f16* const zsS = (f16*)smem_raw + 8704;     // skip:        [64][136]

    const int tid  = threadIdx.x;
    const int lane = tid & 63;
    const int w4   = tid >> 6;
    const int mg   = w4 & 1;
    const int ng   = w4 >> 1;
    const int col  = lane & 15;
    const int quad = lane >> 4;
    const int b    = blockIdx.y;
    const int bx   = blockIdx.x;
    const int xt   = ((bx & 7) << 5) | (bx >> 3);   // XCD-chunked swizzle
    const int t0   = xt * 64;

    const f16* hb = h_in + (size_t)b * T_LEN * 128;
    const int bswz = (quad ^ ((col >> 1) & 3)) * 8;

    f32x4 acc[2][8];
#pragma unroll
    for (int mt = 0; mt < 2; ++mt)
#pragma unroll
        for (int nt = 0; nt < 8; ++nt) acc[mt][nt] = (f32x4)0.0f;

    f16x8 a[2][4];
    // whole-tap A-load; zero-page ADDRESS select (no value selects)
    auto loadA = [&](int tap) {
        const int off = (2 - tap) * d;
#pragma unroll
        for (int mt = 0; mt < 2; ++mt) {
            int t = t0 + mg * 32 + mt * 16 + col - off;
            const f16* base = (t >= 0) ? &hb[(size_t)t * 128] : zpad;
#pragma unroll
            for (int cc = 0; cc < 4; ++cc)
                a[mt][cc] = *(const f16x8*)&base[quad * 8 + cc * 32];
        }
    };

    f16x8 fr[2][4];   // cross-era B-fragment double buffer

    // ---------------- Phase 1: pre = h * WA, 24 eras + drain -----------------
    {   // prologue: DMA chunks 0,1 FIRST, then tap-0 A (A stays in flight)
#pragma unroll
        for (int hh = 0; hh < 2; ++hh) {
            const f16* s = wA + hh * 4096 + w4 * 1024 + lane * 8;
            f16* dd = Bsm + hh * 4096 + w4 * 1024;
            stage16(s, dd); stage16(s + 512, dd + 512);
        }
        PIN();
        loadA(0);
        PIN();
        // queue {D0 x2, D1 x2, A x8}: retire D0, keep D1 + A
        asm volatile("s_waitcnt vmcnt(10)" ::: "memory");
        __builtin_amdgcn_s_barrier();
        PIN();
    }

#pragma unroll
    for (int hc = 0; hc < 24; ++hc) {
        if (hc + 2 < 24) {   // DMA two eras ahead
            const f16* s = wA + (hc + 2) * 4096 + w4 * 1024 + lane * 8;
            f16* dd = Bsm + ((hc + 2) & 3) * 4096 + w4 * 1024;
            stage16(s, dd); stage16(s + 512, dd + 512);
        }
        PIN();
        {   // read THIS chunk's fragments (consumed NEXT era)
            const f16* bsc = Bsm + (hc & 3) * 4096;
#pragma unroll
            for (int ntl = 0; ntl < 4; ++ntl) {
                int row = ng * 64 + ntl * 16 + col;
                fr[hc & 1][ntl] = *(const f16x8*)&bsc[row * 32 + bswz];
            }
        }
        PIN();
        if (hc > 0) {   // MFMA on chunk hc-1, fragments read one era ago
            const int c     = hc - 1;
            const int kc    = (c >> 1) & 3;
            const int nbase = (c & 1) * 4;
            __builtin_amdgcn_s_setprio(1);
#pragma unroll
            for (int ntl = 0; ntl < 4; ++ntl) {
                acc[0][nbase + ntl] = MFMA_F16(a[0][kc], fr[c & 1][ntl], acc[0][nbase + ntl], 0, 0, 0);
                acc[1][nbase + ntl] = MFMA_F16(a[1][kc], fr[c & 1][ntl], acc[1][nbase + ntl], 0, 0, 0);
            }
            __builtin_amdgcn_s_setprio(0);
        }
        PIN();
        // tap-boundary A reload AFTER the last MFMA using the old tap
        if (hc == 8)  loadA(1);
        if (hc == 16) loadA(2);
        PIN();
        // era-end wait (exact under pins; see header ledger)
        if (hc == 0 || hc == 8 || hc == 16) {
            asm volatile("s_waitcnt vmcnt(10)" ::: "memory");
        } else if (hc == 22) {
            asm volatile("s_waitcnt vmcnt(0)" ::: "memory");
        } else if (hc < 22) {
            asm volatile("s_waitcnt vmcnt(2)" ::: "memory");
        }
        if (hc < 23) __builtin_amdgcn_s_barrier();
        PIN();
    }
    {   // drain: chunk 23 (kc=3, gates)
        __builtin_amdgcn_s_setprio(1);
#pragma unroll
        for (int ntl = 0; ntl < 4; ++ntl) {
            acc[0][4 + ntl] = MFMA_F16(a[0][3], fr[1][ntl], acc[0][4 + ntl], 0, 0, 0);
            acc[1][4 + ntl] = MFMA_F16(a[1][3], fr[1][ntl], acc[1][4 + ntl], 0, 0, 0);
        }
        __builtin_amdgcn_s_setprio(0);
    }
    __syncthreads();   // all Bsm reads done before z overlays

    // ---- prefetch phase-2 ch0 B-frags (independent of zs; covered by gating)
    f16x8 b0[8];
#pragma unroll
    for (int nt = 0; nt < 8; ++nt) {
        int nb = (nt < 4) ? (ng * 64 + nt * 16)
                          : (128 + ng * 64 + (nt - 4) * 16);
        b0[nt] = *(const f16x8*)&wB[(size_t)(nb + col) * 32 + quad * 8];
    }

    // ---------------- Gating -> zsR (3-trans fused tanh*sigmoid) ------------
#pragma unroll
    for (int nt = 0; nt < 4; ++nt) {
        int j = ng * 64 + nt * 16 + col;
        float cf = cb[j];
        float cg = cb[j + 128];
#pragma unroll
        for (int mt = 0; mt < 2; ++mt)
#pragma unroll
            for (int reg = 0; reg < 4; ++reg) {
                float f = acc[mt][nt][reg]     + cf;
                float g = acc[mt][nt + 4][reg] + cg;
                float E = __builtin_amdgcn_exp2f(2.885390082f * f); // e^(2f)
                float S = __builtin_amdgcn_exp2f(1.442695041f * g); // e^(g)
                float z = (E - 1.0f) * S *
                          __builtin_amdgcn_rcpf((E + 1.0f) * (S + 1.0f));
                zsR[(mg * 32 + mt * 16 + quad * 4 + reg) * 136 + j] = (f16)z;
            }
    }
    __syncthreads();

    // ---------------- Phase 2: [res|skip] = z * WB, K=128  (r9 verbatim) ----
#pragma unroll
    for (int mt = 0; mt < 2; ++mt)
#pragma unroll
        for (int nt = 0; nt < 8; ++nt) acc[mt][nt] = (f32x4)0.0f;

#pragma unroll
    for (int ch = 0; ch < 4; ++ch) {
        f16x8 a2[2];
#pragma unroll
        for (int mt = 0; mt < 2; ++mt)
            a2[mt] = *(const f16x8*)&zsR[(mg * 32 + mt * 16 + col) * 136 + ch * 32 + quad * 8];
        const f16* wc = wB + ch * 8192;
#pragma unroll
        for (int nt = 0; nt < 8; ++nt) {
            int nb = (nt < 4) ? (ng * 64 + nt * 16)
                              : (128 + ng * 64 + (nt - 4) * 16);
            f16x8 bf = (ch == 0) ? b0[nt]
                                 : *(const f16x8*)&wc[(nb + col) * 32 + quad * 8];
            acc[0][nt] = MFMA_F16(a2[0], bf, acc[0][nt], 0, 0, 0);
            acc[1][nt] = MFMA_F16(a2[1], bf, acc[1][nt], 0, 0, 0);
        }
    }

    // ---- epilogue global loads issued HERE: covered by 2 barriers + writes
    const int orow = tid >> 2, oseg = tid & 3;
    const size_t gb = (size_t)b * T_LEN * 128 + (size_t)(t0 + orow) * 128 + oseg * 32;
    f16x8 hv[4], av[4];
#pragma unroll
    for (int i = 0; i < 4; ++i) hv[i] = *(const f16x8*)&h_in[gb + i * 8];
#pragma unroll
    for (int i = 0; i < 4; ++i) av[i] = *(const f16x8*)&acc1[gb + i * 8];

    __syncthreads();   // z reads drained before res overwrites zsR

    // ---------------- Merged epilogue: res->zsR, skip->zsS, one barrier -----
#pragma unroll
    for (int nt = 0; nt < 4; ++nt) {
        int n = ng * 64 + nt * 16 + col;
        float o = ob[n];
#pragma unroll
        for (int mt = 0; mt < 2; ++mt)
#pragma unroll
            for (int reg = 0; reg < 4; ++reg) {
                int r = (mg * 32 + mt * 16 + quad * 4 + reg) * 136 + n;
                zsR[r] = (f16)(acc[mt][nt][reg] + o);
                zsS[r] = (f16)acc[mt][nt + 4][reg];
            }
    }
    __syncthreads();
#pragma unroll
    for (int i = 0; i < 4; ++i) {
        f16x8 rv = *(const f16x8*)&zsR[orow * 136 + oseg * 32 + i * 8];
        *(f16x8*)&h_out[gb + i * 8] = hv[i] + rv;
    }
#pragma unroll
    for (int i = 0; i < 4; ++i) {
        f16x8 sv = *(const f16x8*)&zsS[orow * 136 + oseg * 32 + i * 8];
        *(f16x8*)&acc1[gb + i * 8] = av[i] + sv;
    }
}

// out[bt] = o2b + sum_r o2w[r] * tanh(acc1[bt][r] + o1b[r]); one wave per bt
__global__ __launch_bounds__(256) void final_kernel(
    const f16* __restrict__ acc1, const float* __restrict__ b1,
    const float* __restrict__ w2, const float* __restrict__ b2,
    float* __restrict__ out)
{
    int lane = threadIdx.x & 63;
    int w = threadIdx.x >> 6;
    int bt = blockIdx.x * 4 + w;
    float v0 = (float)acc1[(size_t)bt * 128 + lane];
    float v1 = (float)acc1[(size_t)bt * 128 + lane + 64];
    float s = w2[lane] * fast_tanh(v0 + b1[lane]) +
              w2[lane + 64] * fast_tanh(v1 + b1[lane + 64]);
#pragma unroll
    for (int k = 1; k < 64; k <<= 1) s += __shfl_xor(s, k, 64);
    if (lane == 0) out[bt] = s + b2[0];
}

extern "C" void kernel_launch(void* const* d_in, const int* in_sizes, int n_in,
                              void* d_out, int out_size, void* d_ws, size_t ws_size,
                              hipStream_t stream)
{
    const float* x   = (const float*)d_in[0];
    const float* iw  = (const float*)d_in[1];
    const float* ib  = (const float*)d_in[2];
    const float* cw  = (const float*)d_in[3];
    const float* cb  = (const float*)d_in[4];
    const float* ow  = (const float*)d_in[5];
    const float* ob  = (const float*)d_in[6];
    const float* o1w = (const float*)d_in[7];
    const float* o1b = (const float*)d_in[8];
    const float* o2w = (const float*)d_in[9];
    const float* o2b = (const float*)d_in[10];
    float* out = (float*)d_out;

    const size_t HTR = (size_t)BATCH * T_LEN * 128;   // 16777216
    f16* hA   = (f16*)d_ws;
    f16* hB   = hA + HTR;
    f16* acc1 = hB + HTR;
    f16* wAp  = acc1 + HTR;
    f16* wBp  = wAp + (size_t)NLAYER * 12 * 256 * 32;
    f16* zpad = wBp + (size_t)NLAYER * 4 * 256 * 32;  // 128 f16 zeros
    // total ~ 3*32 MB + 2.4 MB = ~103 MB of ws

    // 4610 blocks: covers NA + NB + 128 (zpad) with the bounds checks
    prep_weights<<<4610, 256, 0, stream>>>(cw, ow, o1w, wAp, wBp);
    input_init<<<65536, 256, 0, stream>>>(x, iw, ib, hA, acc1);

    const int DIL[NLAYER] = {1, 2, 4, 8, 16, 32, 64, 128, 256};
    f16* hin = hA; f16* hout = hB;
    for (int l = 0; l < NLAYER; ++l) {
        layer_kernel<<<dim3(T_LEN / 64, BATCH), 256, 0, stream>>>(
            hin, hout, acc1,
            wAp + (size_t)l * 12 * 256 * 32, wBp + (size_t)l * 4 * 256 * 32,
            zpad, cb + l * 256, ob + l * 128, DIL[l]);
        f16* tmp = hin; hin = hout; hout = tmp;
    }
    final_kernel<<<BATCH * T_LEN / 4, 256, 0, stream>>>(acc1, o1b, o2w, o2b, out);
}